// Round 1
// baseline (374.820 us; speedup 1.0000x reference)
//
#include <hip/hip_runtime.h>
#include <math.h>

#define BB 32
#define TT 1024
#define DD 256
#define PP 20
constexpr float EPS = 1e-12f;

// ---------------------------------------------------------------------------
// Kernel 1: row L2 normalize. rows = BB*TT, each of DD floats.
// One wave (64 lanes) per row, float4 per lane. 4 rows per 256-thread block.
// ---------------------------------------------------------------------------
__global__ __launch_bounds__(256) void k_rownorm(const float* __restrict__ in,
                                                 float* __restrict__ out) {
    const int wave = threadIdx.x >> 6;
    const int lane = threadIdx.x & 63;
    const size_t row = (size_t)blockIdx.x * 4 + wave;
    float4 v = reinterpret_cast<const float4*>(in + row * DD)[lane];
    float s = v.x * v.x + v.y * v.y + v.z * v.z + v.w * v.w;
#pragma unroll
    for (int off = 32; off; off >>= 1) s += __shfl_xor(s, off);
    const float sc = 1.0f / sqrtf(fmaxf(s, EPS));
    v.x *= sc; v.y *= sc; v.z *= sc; v.w *= sc;
    reinterpret_cast<float4*>(out + row * DD)[lane] = v;
}

// ---------------------------------------------------------------------------
// Kernel 2: alpha[b][d][e] = sum_t ob[b][t][d] * oa[b][t][e]
// Per-batch GEMM: (D x T) * (T x D), K = T = 1024. Both operands are read
// as [t][col] (k-major) so staging is directly coalesced, no transpose.
// 64x64 tile, 256 threads, 4x4 acc per thread, KT=16.
// grid = (16 tiles, B)
// ---------------------------------------------------------------------------
__global__ __launch_bounds__(256) void k_alpha(const float* __restrict__ oa,
                                               const float* __restrict__ ob,
                                               float* __restrict__ alpha) {
    __shared__ float As[16][64];  // ob slice  [k][d-local]
    __shared__ float Bs[16][64];  // oa slice  [k][e-local]
    const int b = blockIdx.y;
    const int d0 = (blockIdx.x >> 2) * 64;
    const int e0 = (blockIdx.x & 3) * 64;
    const float* pb = ob + (size_t)b * TT * DD;
    const float* pa = oa + (size_t)b * TT * DD;
    const int tx = threadIdx.x & 15;   // e sub-tile
    const int ty = threadIdx.x >> 4;   // d sub-tile
    const int lr = threadIdx.x >> 6;   // staging row group (0..3)
    const int lc = threadIdx.x & 63;   // staging col
    float acc[4][4] = {};
    for (int k0 = 0; k0 < TT; k0 += 16) {
#pragma unroll
        for (int r = 0; r < 16; r += 4) {
            As[r + lr][lc] = pb[(size_t)(k0 + r + lr) * DD + d0 + lc];
            Bs[r + lr][lc] = pa[(size_t)(k0 + r + lr) * DD + e0 + lc];
        }
        __syncthreads();
#pragma unroll
        for (int k = 0; k < 16; ++k) {
            const float4 a4 = *reinterpret_cast<const float4*>(&As[k][ty * 4]);
            const float4 b4 = *reinterpret_cast<const float4*>(&Bs[k][tx * 4]);
            const float av[4] = {a4.x, a4.y, a4.z, a4.w};
            const float bv[4] = {b4.x, b4.y, b4.z, b4.w};
#pragma unroll
            for (int i = 0; i < 4; ++i)
#pragma unroll
                for (int j = 0; j < 4; ++j) acc[i][j] += av[i] * bv[j];
        }
        __syncthreads();
    }
    float* out = alpha + ((size_t)b * DD + d0) * DD + e0;
#pragma unroll
    for (int i = 0; i < 4; ++i) {
        const float4 v = {acc[i][0], acc[i][1], acc[i][2], acc[i][3]};
        *reinterpret_cast<float4*>(&out[(size_t)(ty * 4 + i) * DD + tx * 4]) = v;
    }
}

// ---------------------------------------------------------------------------
// Kernel 3: normalize alpha over axis d (axis=1 of (B,D,E)).
// Block = 256 threads handles 64 e-columns of one batch; the d-range is
// split across the 4 waves, partials combined through LDS.
// grid = (4 e-chunks, B)
// ---------------------------------------------------------------------------
__global__ __launch_bounds__(256) void k_alphanorm(float* __restrict__ alpha) {
    __shared__ float part[4][64];
    const int b = blockIdx.y;
    const int e0 = blockIdx.x * 64;
    const int w = threadIdx.x >> 6;
    const int lane = threadIdx.x & 63;
    float* base = alpha + (size_t)b * DD * DD + e0 + lane;
    float s = 0.f;
#pragma unroll 8
    for (int d = w * 64; d < w * 64 + 64; ++d) {
        const float v = base[(size_t)d * DD];
        s += v * v;
    }
    part[w][lane] = s;
    __syncthreads();
    const float tot = part[0][lane] + part[1][lane] + part[2][lane] + part[3][lane];
    const float sc = 1.0f / sqrtf(fmaxf(tot, EPS));
#pragma unroll 8
    for (int d = w * 64; d < w * 64 + 64; ++d) base[(size_t)d * DD] *= sc;
}

// ---------------------------------------------------------------------------
// Kernel 4: hmean[b][t][e] = sum_d ob[b][t][d] * alpha[b][d][e]
// Per-batch GEMM: (T x D) * (D x D). M=1024, N=256, K=256.
// A (ob) is M-major so it is transpose-staged into As[k][m] (pad 68 to kill
// write bank conflicts while keeping float4 alignment). KT=16, 64x64 tiles.
// grid = (4, 16, B)
// ---------------------------------------------------------------------------
__global__ __launch_bounds__(256) void k_hmean(const float* __restrict__ ob,
                                               const float* __restrict__ alpha,
                                               float* __restrict__ hm) {
    __shared__ float As[16][68];  // [k][t-local], padded
    __shared__ float Bs[16][64];  // [k][e-local]
    const int b = blockIdx.z;
    const int t0 = blockIdx.y * 64;
    const int e0 = blockIdx.x * 64;
    const float* pA = ob + (size_t)b * TT * DD;
    const float* pB = alpha + (size_t)b * DD * DD;
    const int tx = threadIdx.x & 15;
    const int ty = threadIdx.x >> 4;
    const int lr = threadIdx.x >> 6;
    const int lc = threadIdx.x & 63;
    const int ar = threadIdx.x >> 4;  // 0..15: t-row group for A loads
    const int ac = threadIdx.x & 15;  // 0..15: k col for A loads
    float acc[4][4] = {};
    for (int k0 = 0; k0 < DD; k0 += 16) {
#pragma unroll
        for (int r = 0; r < 64; r += 16)
            As[ac][r + ar] = pA[(size_t)(t0 + r + ar) * DD + k0 + ac];
#pragma unroll
        for (int r = 0; r < 16; r += 4)
            Bs[r + lr][lc] = pB[(size_t)(k0 + r + lr) * DD + e0 + lc];
        __syncthreads();
#pragma unroll
        for (int k = 0; k < 16; ++k) {
            const float4 a4 = *reinterpret_cast<const float4*>(&As[k][ty * 4]);
            const float4 b4 = *reinterpret_cast<const float4*>(&Bs[k][tx * 4]);
            const float av[4] = {a4.x, a4.y, a4.z, a4.w};
            const float bv[4] = {b4.x, b4.y, b4.z, b4.w};
#pragma unroll
            for (int i = 0; i < 4; ++i)
#pragma unroll
                for (int j = 0; j < 4; ++j) acc[i][j] += av[i] * bv[j];
        }
        __syncthreads();
    }
    float* out = hm + ((size_t)b * TT + t0) * DD + e0;
#pragma unroll
    for (int i = 0; i < 4; ++i) {
        const float4 v = {acc[i][0], acc[i][1], acc[i][2], acc[i][3]};
        *reinterpret_cast<float4*>(&out[(size_t)(ty * 4 + i) * DD + tx * 4]) = v;
    }
}

// ---------------------------------------------------------------------------
// Kernel 5: persp[b][t][p] = num / (sqrt(max(sa,eps))*sqrt(max(sh,eps)))
//   num = sum_d a*h*W2[p][d]; sa = sum_d a*a*W2; sh = sum_d h*h*W2
// One wave per (b,t) row; W2 staged in LDS; butterfly reduce per p.
// grid = BB*TT/4 blocks of 256.
// ---------------------------------------------------------------------------
__global__ __launch_bounds__(256) void k_persp(const float* __restrict__ inp_a,
                                               const float* __restrict__ hmean,
                                               const float* __restrict__ W,
                                               float* __restrict__ out) {
    __shared__ float w2[PP][DD];  // 20 KB
    for (int i = threadIdx.x; i < PP * DD; i += 256) {
        const float w = W[i];
        (&w2[0][0])[i] = w * w;
    }
    __syncthreads();
    const int wave = threadIdx.x >> 6;
    const int lane = threadIdx.x & 63;
    const size_t row = (size_t)blockIdx.x * 4 + wave;
    const float4 a = reinterpret_cast<const float4*>(inp_a + row * DD)[lane];
    const float4 h = reinterpret_cast<const float4*>(hmean + row * DD)[lane];
    const float ah[4] = {a.x * h.x, a.y * h.y, a.z * h.z, a.w * h.w};
    const float aa[4] = {a.x * a.x, a.y * a.y, a.z * a.z, a.w * a.w};
    const float hh[4] = {h.x * h.x, h.y * h.y, h.z * h.z, h.w * h.w};
    float myval = 0.f;
#pragma unroll
    for (int p = 0; p < PP; ++p) {
        const float4 w4 = *reinterpret_cast<const float4*>(&w2[p][lane * 4]);
        const float wv[4] = {w4.x, w4.y, w4.z, w4.w};
        float s1 = 0.f, s2 = 0.f, s3 = 0.f;
#pragma unroll
        for (int i = 0; i < 4; ++i) {
            s1 += ah[i] * wv[i];
            s2 += aa[i] * wv[i];
            s3 += hh[i] * wv[i];
        }
#pragma unroll
        for (int off = 32; off; off >>= 1) {
            s1 += __shfl_xor(s1, off);
            s2 += __shfl_xor(s2, off);
            s3 += __shfl_xor(s3, off);
        }
        const float r = s1 / (sqrtf(fmaxf(s2, EPS)) * sqrtf(fmaxf(s3, EPS)));
        if (lane == p) myval = r;
    }
    if (lane < PP) {
        const size_t o = row * PP + lane;
        out[o] = myval;
        out[(size_t)BB * TT * PP + o] = myval;  // second tuple element (identical)
    }
}

// ---------------------------------------------------------------------------
extern "C" void kernel_launch(void* const* d_in, const int* in_sizes, int n_in,
                              void* d_out, int out_size, void* d_ws, size_t ws_size,
                              hipStream_t stream) {
    const float* inp_a = (const float*)d_in[0];
    const float* inp_b = (const float*)d_in[1];
    const float* W = (const float*)d_in[2];
    float* out = (float*)d_out;

    float* oa = (float*)d_ws;                       // 32*1024*256 floats
    float* ob = oa + (size_t)BB * TT * DD;          // 32*1024*256 floats
    float* alpha = ob + (size_t)BB * TT * DD;       // 32*256*256 floats
    float* hmean = oa;                              // reuse: oa dead after k_alpha

    // 1. row normalize both inputs
    k_rownorm<<<BB * TT / 4, 256, 0, stream>>>(inp_a, oa);
    k_rownorm<<<BB * TT / 4, 256, 0, stream>>>(inp_b, ob);
    // 2. alpha = ob^T @ oa per batch
    k_alpha<<<dim3(16, BB), 256, 0, stream>>>(oa, ob, alpha);
    // 3. normalize alpha over d
    k_alphanorm<<<dim3(4, BB), 256, 0, stream>>>(alpha);
    // 4. hmean = ob @ alpha per batch (writes over oa buffer)
    k_hmean<<<dim3(4, 16, BB), 256, 0, stream>>>(ob, alpha, hmean);
    // 5. perspectives
    k_persp<<<BB * TT / 4, 256, 0, stream>>>(inp_a, hmean, W, out);
}

// Round 3
// 330.008 us; speedup vs baseline: 1.1358x; 1.1358x over previous
//
#include <hip/hip_runtime.h>
#include <math.h>

#define BB 32
#define TT 1024
#define DD 256
#define PP 20
constexpr float EPS = 1e-12f;

// ---------------------------------------------------------------------------
// Kernel 1: row L2 normalize. rows = BB*TT, each of DD floats.
// One wave (64 lanes) per row, float4 per lane. 4 rows per 256-thread block.
// ---------------------------------------------------------------------------
__global__ __launch_bounds__(256) void k_rownorm(const float* __restrict__ in,
                                                 float* __restrict__ out) {
    const int wave = threadIdx.x >> 6;
    const int lane = threadIdx.x & 63;
    const size_t row = (size_t)blockIdx.x * 4 + wave;
    float4 v = reinterpret_cast<const float4*>(in + row * DD)[lane];
    float s = v.x * v.x + v.y * v.y + v.z * v.z + v.w * v.w;
#pragma unroll
    for (int off = 32; off; off >>= 1) s += __shfl_xor(s, off);
    const float sc = 1.0f / sqrtf(fmaxf(s, EPS));
    v.x *= sc; v.y *= sc; v.z *= sc; v.w *= sc;
    reinterpret_cast<float4*>(out + row * DD)[lane] = v;
}

// ---------------------------------------------------------------------------
// Kernel 2: alpha_part[h][b][d][e] = sum_{t in half h} ob[b][t][d]*oa[b][t][e]
// Per-batch GEMM (D x T)*(T x D), split-K=2. Tile 128(d) x 64(e), KT=16,
// 256 threads, 8x4 acc/thread (32 FMA : 3 LDS b128 per k).
// grid = (8 tiles, 2 k-halves, B)
// ---------------------------------------------------------------------------
__global__ __launch_bounds__(256) void k_alpha(const float* __restrict__ oa,
                                               const float* __restrict__ ob,
                                               float* __restrict__ apart) {
    __shared__ float As[16][128];  // ob slice [k][d-local]
    __shared__ float Bs[16][64];   // oa slice [k][e-local]
    const int tid = threadIdx.x;
    const int b = blockIdx.z;
    const int d0 = (blockIdx.x >> 2) * 128;
    const int e0 = (blockIdx.x & 3) * 64;
    const int kbeg = blockIdx.y * (TT / 2);
    const float* pb = ob + (size_t)b * TT * DD;
    const float* pa = oa + (size_t)b * TT * DD;
    const int m0 = (tid >> 4) * 8;
    const int n0 = (tid & 15) * 4;
    float acc[8][4] = {};
    for (int k0 = kbeg; k0 < kbeg + TT / 2; k0 += 16) {
#pragma unroll
        for (int rep = 0; rep < 2; ++rep) {
            const int kr = rep * 8 + (tid >> 5);
            const int dc = (tid & 31) * 4;
            *reinterpret_cast<float4*>(&As[kr][dc]) =
                *reinterpret_cast<const float4*>(&pb[(size_t)(k0 + kr) * DD + d0 + dc]);
        }
        {
            const int kr = tid >> 4;
            const int ec = (tid & 15) * 4;
            *reinterpret_cast<float4*>(&Bs[kr][ec]) =
                *reinterpret_cast<const float4*>(&pa[(size_t)(k0 + kr) * DD + e0 + ec]);
        }
        __syncthreads();
#pragma unroll
        for (int k = 0; k < 16; ++k) {
            const float4 a0 = *reinterpret_cast<const float4*>(&As[k][m0]);
            const float4 a1 = *reinterpret_cast<const float4*>(&As[k][m0 + 4]);
            const float4 b4 = *reinterpret_cast<const float4*>(&Bs[k][n0]);
            const float av[8] = {a0.x, a0.y, a0.z, a0.w, a1.x, a1.y, a1.z, a1.w};
            const float bv[4] = {b4.x, b4.y, b4.z, b4.w};
#pragma unroll
            for (int i = 0; i < 8; ++i)
#pragma unroll
                for (int j = 0; j < 4; ++j) acc[i][j] += av[i] * bv[j];
        }
        __syncthreads();
    }
    float* out = apart + (size_t)blockIdx.y * BB * DD * DD +
                 ((size_t)b * DD + d0) * DD + e0;
#pragma unroll
    for (int i = 0; i < 8; ++i) {
        const float4 v = {acc[i][0], acc[i][1], acc[i][2], acc[i][3]};
        *reinterpret_cast<float4*>(&out[(size_t)(m0 + i) * DD + n0]) = v;
    }
}

// ---------------------------------------------------------------------------
// Kernel 3: alpha = l2norm_over_d(apart0 + apart1). Sums the split-K halves,
// normalizes each (b, :, e) column, writes final alpha into dst (= apart0).
// Each thread owns 64 d's of one e-column; partials combined via LDS.
// grid = (4 e-chunks, B)
// ---------------------------------------------------------------------------
__global__ __launch_bounds__(256) void k_alphanorm(const float* __restrict__ p0,
                                                   const float* __restrict__ p1,
                                                   float* __restrict__ dst) {
    __shared__ float part[4][64];
    const int b = blockIdx.y;
    const int e0 = blockIdx.x * 64;
    const int w = threadIdx.x >> 6;
    const int lane = threadIdx.x & 63;
    const size_t base = (size_t)b * DD * DD + e0 + lane;
    float vbuf[64];
    float s = 0.f;
#pragma unroll
    for (int d = 0; d < 64; ++d) {
        const size_t idx = base + (size_t)(w * 64 + d) * DD;
        const float v = p0[idx] + p1[idx];
        vbuf[d] = v;
        s += v * v;
    }
    part[w][lane] = s;
    __syncthreads();
    const float tot = part[0][lane] + part[1][lane] + part[2][lane] + part[3][lane];
    const float sc = 1.0f / sqrtf(fmaxf(tot, EPS));
#pragma unroll
    for (int d = 0; d < 64; ++d) dst[base + (size_t)(w * 64 + d) * DD] = vbuf[d] * sc;
}

// ---------------------------------------------------------------------------
// Kernel 4: hmean[b][t][e] = sum_d ob[b][t][d] * alpha[b][d][e]
// Tile 128(t) x 64(e), KT=16, 256 threads, 8x4 acc/thread. A transpose-staged
// into As[k][m] (pad 132 keeps float4 alignment, 2-way banks on write = free).
// grid = (4 e-tiles, 8 t-tiles, B)
// ---------------------------------------------------------------------------
__global__ __launch_bounds__(256) void k_hmean(const float* __restrict__ ob,
                                               const float* __restrict__ alpha,
                                               float* __restrict__ hm) {
    __shared__ float As[16][132];  // [k][t-local]
    __shared__ float Bs[16][64];   // [k][e-local]
    const int tid = threadIdx.x;
    const int b = blockIdx.z;
    const int t0 = blockIdx.y * 128;
    const int e0 = blockIdx.x * 64;
    const float* pA = ob + (size_t)b * TT * DD;
    const float* pB = alpha + (size_t)b * DD * DD;
    const int m0 = (tid >> 4) * 8;
    const int n0 = (tid & 15) * 4;
    float acc[8][4] = {};
    for (int k0 = 0; k0 < DD; k0 += 16) {
#pragma unroll
        for (int rep = 0; rep < 2; ++rep) {
            const int mm = rep * 64 + (tid >> 2);
            const int kk4 = (tid & 3) * 4;
            const float4 v =
                *reinterpret_cast<const float4*>(&pA[(size_t)(t0 + mm) * DD + k0 + kk4]);
            As[kk4 + 0][mm] = v.x;
            As[kk4 + 1][mm] = v.y;
            As[kk4 + 2][mm] = v.z;
            As[kk4 + 3][mm] = v.w;
        }
        {
            const int kr = tid >> 4;
            const int ec = (tid & 15) * 4;
            *reinterpret_cast<float4*>(&Bs[kr][ec]) =
                *reinterpret_cast<const float4*>(&pB[(size_t)(k0 + kr) * DD + e0 + ec]);
        }
        __syncthreads();
#pragma unroll
        for (int k = 0; k < 16; ++k) {
            const float4 a0 = *reinterpret_cast<const float4*>(&As[k][m0]);
            const float4 a1 = *reinterpret_cast<const float4*>(&As[k][m0 + 4]);
            const float4 b4 = *reinterpret_cast<const float4*>(&Bs[k][n0]);
            const float av[8] = {a0.x, a0.y, a0.z, a0.w, a1.x, a1.y, a1.z, a1.w};
            const float bv[4] = {b4.x, b4.y, b4.z, b4.w};
#pragma unroll
            for (int i = 0; i < 8; ++i)
#pragma unroll
                for (int j = 0; j < 4; ++j) acc[i][j] += av[i] * bv[j];
        }
        __syncthreads();
    }
    float* out = hm + ((size_t)b * TT + t0 + m0) * DD + e0 + n0;
#pragma unroll
    for (int i = 0; i < 8; ++i) {
        const float4 v = {acc[i][0], acc[i][1], acc[i][2], acc[i][3]};
        *reinterpret_cast<float4*>(&out[(size_t)i * DD]) = v;
    }
}

// ---------------------------------------------------------------------------
// Kernel 5 (rewritten): persp[b][t][p] = num / (sqrt(sa)*sqrt(sh)).
// Lane layout: 8 lanes per row (each owns 32 d's), 8 rows per wave.
// Each thread accumulates all 20p x 3sums = 60 partials in registers over its
// d-slice (1920 FMA), then 3-level shfl_xor reduction (180 shfl, 9% overhead).
// W^2 staged in LDS as [p][q][quad(pad 9)][4] so the 8 q-groups read 8
// distinct banks (broadcast within group) - conflict-free b128.
// grid = BB*TT/32 blocks of 256.
// ---------------------------------------------------------------------------
__global__ __launch_bounds__(256) void k_persp(const float* __restrict__ inp_a,
                                               const float* __restrict__ hmean,
                                               const float* __restrict__ W,
                                               float* __restrict__ out) {
    __shared__ float w2L[PP * 8 * 9 * 4];  // ((p*8+q)*9+quad)*4+j : 11.5 KB
    for (int i = threadIdx.x; i < PP * 256; i += 256) {
        const int p = i >> 8;
        const int q = (i >> 5) & 7;
        const int quad = (i >> 2) & 7;
        const int j = i & 3;
        const float w = W[p * DD + q * 32 + quad * 4 + j];
        w2L[((p * 8 + q) * 9 + quad) * 4 + j] = w * w;
    }
    __syncthreads();
    const int wave = threadIdx.x >> 6;
    const int lane = threadIdx.x & 63;
    const int r = lane & 7;   // row within wave
    const int q = lane >> 3;  // d-slice (32 d's)
    const size_t row = (size_t)blockIdx.x * 32 + wave * 8 + r;
    const float* pa = inp_a + row * DD + q * 32;
    const float* ph = hmean + row * DD + q * 32;
    const float4* w2q = reinterpret_cast<const float4*>(w2L);

    float acc[PP][3] = {};
    for (int quad = 0; quad < 8; ++quad) {
        const float4 a4 = *reinterpret_cast<const float4*>(pa + quad * 4);
        const float4 h4 = *reinterpret_cast<const float4*>(ph + quad * 4);
        const float ah[4] = {a4.x * h4.x, a4.y * h4.y, a4.z * h4.z, a4.w * h4.w};
        const float aa[4] = {a4.x * a4.x, a4.y * a4.y, a4.z * a4.z, a4.w * a4.w};
        const float hh[4] = {h4.x * h4.x, h4.y * h4.y, h4.z * h4.z, h4.w * h4.w};
#pragma unroll
        for (int p = 0; p < PP; ++p) {
            const float4 w4 = w2q[(p * 8 + q) * 9 + quad];
            const float wv[4] = {w4.x, w4.y, w4.z, w4.w};
#pragma unroll
            for (int j = 0; j < 4; ++j) {
                acc[p][0] += ah[j] * wv[j];
                acc[p][1] += aa[j] * wv[j];
                acc[p][2] += hh[j] * wv[j];
            }
        }
    }
    // reduce the 8 q-slices of each row (lanes differing in bits 3,4,5)
#pragma unroll
    for (int p = 0; p < PP; ++p)
#pragma unroll
        for (int s = 0; s < 3; ++s) {
            float v = acc[p][s];
            v += __shfl_xor(v, 8);
            v += __shfl_xor(v, 16);
            v += __shfl_xor(v, 32);
            acc[p][s] = v;
        }
    if (q == 0) {
        float res[PP];
#pragma unroll
        for (int p = 0; p < PP; ++p) {
            const float sa = sqrtf(fmaxf(acc[p][1], EPS));
            const float sh = sqrtf(fmaxf(acc[p][2], EPS));
            res[p] = acc[p][0] / (sa * sh);
        }
        float* o1 = out + row * PP;
        float* o2 = o1 + (size_t)BB * TT * PP;
#pragma unroll
        for (int k = 0; k < 5; ++k) {
            const float4 v = reinterpret_cast<const float4*>(res)[k];
            reinterpret_cast<float4*>(o1)[k] = v;
            reinterpret_cast<float4*>(o2)[k] = v;
        }
    }
}

// ---------------------------------------------------------------------------
extern "C" void kernel_launch(void* const* d_in, const int* in_sizes, int n_in,
                              void* d_out, int out_size, void* d_ws, size_t ws_size,
                              hipStream_t stream) {
    const float* inp_a = (const float*)d_in[0];
    const float* inp_b = (const float*)d_in[1];
    const float* W = (const float*)d_in[2];
    float* out = (float*)d_out;

    float* oa = (float*)d_ws;                        // 8.39M floats
    float* ob = oa + (size_t)BB * TT * DD;           // 8.39M floats
    float* apart = ob + (size_t)BB * TT * DD;        // 2 x 2.10M floats
    float* apart1 = apart + (size_t)BB * DD * DD;
    float* alpha = apart;                            // final alpha overwrites half 0
    float* hmean = oa;                               // reuse: oa dead after k_alpha

    k_rownorm<<<BB * TT / 4, 256, 0, stream>>>(inp_a, oa);
    k_rownorm<<<BB * TT / 4, 256, 0, stream>>>(inp_b, ob);
    k_alpha<<<dim3(8, 2, BB), 256, 0, stream>>>(oa, ob, apart);
    k_alphanorm<<<dim3(4, BB), 256, 0, stream>>>(apart, apart1, alpha);
    k_hmean<<<dim3(4, 8, BB), 256, 0, stream>>>(ob, alpha, hmean);
    k_persp<<<BB * TT / 32, 256, 0, stream>>>(inp_a, hmean, W, out);
}

// Round 4
// 272.601 us; speedup vs baseline: 1.3750x; 1.2106x over previous
//
#include <hip/hip_runtime.h>
#include <math.h>

#define BB 32
#define TT 1024
#define DD 256
#define PP 20
constexpr float EPS = 1e-12f;

// ---------------------------------------------------------------------------
// Kernel 1: row L2 normalize. rows = BB*TT, each of DD floats.
// One wave (64 lanes) per row, float4 per lane. 4 rows per 256-thread block.
// ---------------------------------------------------------------------------
__global__ __launch_bounds__(256) void k_rownorm(const float* __restrict__ in,
                                                 float* __restrict__ out) {
    const int wave = threadIdx.x >> 6;
    const int lane = threadIdx.x & 63;
    const size_t row = (size_t)blockIdx.x * 4 + wave;
    float4 v = reinterpret_cast<const float4*>(in + row * DD)[lane];
    float s = v.x * v.x + v.y * v.y + v.z * v.z + v.w * v.w;
#pragma unroll
    for (int off = 32; off; off >>= 1) s += __shfl_xor(s, off);
    const float sc = 1.0f / sqrtf(fmaxf(s, EPS));
    v.x *= sc; v.y *= sc; v.z *= sc; v.w *= sc;
    reinterpret_cast<float4*>(out + row * DD)[lane] = v;
}

// ---------------------------------------------------------------------------
// Kernel 2: alpha_part[h][b][d][e] = sum_{t in half h} ob[b][t][d]*oa[b][t][e]
// Split-K=2, tile 128(d) x 64(e), KT=16, 256 threads, 8x4 acc.
// Double-buffered LDS, register-prefetch, ONE barrier per k-tile:
//   [load regs t+1] -> barrier -> [compute buf(t)] -> [write buf(t+1)]
// Safe: between barrier(t) and barrier(t+1) waves only read buf(t&1) and
// write buf((t+1)&1) (disjoint), loads for t+1 overlap barrier+compute.
// grid = (8 tiles, 2 k-halves, B)
// ---------------------------------------------------------------------------
__global__ __launch_bounds__(256) void k_alpha(const float* __restrict__ oa,
                                               const float* __restrict__ ob,
                                               float* __restrict__ apart) {
    __shared__ float As[2][16][128];  // [buf][k][d-local]
    __shared__ float Bs[2][16][64];   // [buf][k][e-local]
    const int tid = threadIdx.x;
    const int b = blockIdx.z;
    const int d0 = (blockIdx.x >> 2) * 128;
    const int e0 = (blockIdx.x & 3) * 64;
    const int kbeg = blockIdx.y * (TT / 2);
    const float* pb = ob + (size_t)b * TT * DD;
    const float* pa = oa + (size_t)b * TT * DD;
    const int akr = tid >> 5;         // 0..7
    const int adc = (tid & 31) * 4;   // 0..124
    const int bkr = tid >> 4;         // 0..15
    const int bec = (tid & 15) * 4;   // 0..60
    const int m0 = (tid >> 4) * 8;
    const int n0 = (tid & 15) * 4;
    float4 ra0, ra1, rb;
    float acc[8][4] = {};

    const int NT = (TT / 2) / 16;  // 32 k-tiles
    // prologue: load + write tile 0
    ra0 = *reinterpret_cast<const float4*>(&pb[(size_t)(kbeg + akr) * DD + d0 + adc]);
    ra1 = *reinterpret_cast<const float4*>(&pb[(size_t)(kbeg + 8 + akr) * DD + d0 + adc]);
    rb  = *reinterpret_cast<const float4*>(&pa[(size_t)(kbeg + bkr) * DD + e0 + bec]);
    *reinterpret_cast<float4*>(&As[0][akr][adc]) = ra0;
    *reinterpret_cast<float4*>(&As[0][8 + akr][adc]) = ra1;
    *reinterpret_cast<float4*>(&Bs[0][bkr][bec]) = rb;

    for (int t = 0; t < NT; ++t) {
        if (t + 1 < NT) {
            const int k0 = kbeg + (t + 1) * 16;
            ra0 = *reinterpret_cast<const float4*>(&pb[(size_t)(k0 + akr) * DD + d0 + adc]);
            ra1 = *reinterpret_cast<const float4*>(&pb[(size_t)(k0 + 8 + akr) * DD + d0 + adc]);
            rb  = *reinterpret_cast<const float4*>(&pa[(size_t)(k0 + bkr) * DD + e0 + bec]);
        }
        __syncthreads();
        const int cur = t & 1;
#pragma unroll
        for (int k = 0; k < 16; ++k) {
            const float4 a0 = *reinterpret_cast<const float4*>(&As[cur][k][m0]);
            const float4 a1 = *reinterpret_cast<const float4*>(&As[cur][k][m0 + 4]);
            const float4 b4 = *reinterpret_cast<const float4*>(&Bs[cur][k][n0]);
            const float av[8] = {a0.x, a0.y, a0.z, a0.w, a1.x, a1.y, a1.z, a1.w};
            const float bv[4] = {b4.x, b4.y, b4.z, b4.w};
#pragma unroll
            for (int i = 0; i < 8; ++i)
#pragma unroll
                for (int j = 0; j < 4; ++j) acc[i][j] += av[i] * bv[j];
        }
        if (t + 1 < NT) {
            const int nxt = (t + 1) & 1;
            *reinterpret_cast<float4*>(&As[nxt][akr][adc]) = ra0;
            *reinterpret_cast<float4*>(&As[nxt][8 + akr][adc]) = ra1;
            *reinterpret_cast<float4*>(&Bs[nxt][bkr][bec]) = rb;
        }
    }
    float* out = apart + (size_t)blockIdx.y * BB * DD * DD +
                 ((size_t)b * DD + d0) * DD + e0;
#pragma unroll
    for (int i = 0; i < 8; ++i) {
        const float4 v = {acc[i][0], acc[i][1], acc[i][2], acc[i][3]};
        *reinterpret_cast<float4*>(&out[(size_t)(m0 + i) * DD + n0]) = v;
    }
}

// ---------------------------------------------------------------------------
// Kernel 3: alpha = l2norm_over_d(apart0 + apart1). Sums the split-K halves,
// normalizes each (b, :, e) column, writes final alpha into dst (= apart0).
// grid = (4 e-chunks, B)
// ---------------------------------------------------------------------------
__global__ __launch_bounds__(256) void k_alphanorm(const float* __restrict__ p0,
                                                   const float* __restrict__ p1,
                                                   float* __restrict__ dst) {
    __shared__ float part[4][64];
    const int b = blockIdx.y;
    const int e0 = blockIdx.x * 64;
    const int w = threadIdx.x >> 6;
    const int lane = threadIdx.x & 63;
    const size_t base = (size_t)b * DD * DD + e0 + lane;
    float vbuf[64];
    float s = 0.f;
#pragma unroll
    for (int d = 0; d < 64; ++d) {
        const size_t idx = base + (size_t)(w * 64 + d) * DD;
        const float v = p0[idx] + p1[idx];
        vbuf[d] = v;
        s += v * v;
    }
    part[w][lane] = s;
    __syncthreads();
    const float tot = part[0][lane] + part[1][lane] + part[2][lane] + part[3][lane];
    const float sc = 1.0f / sqrtf(fmaxf(tot, EPS));
#pragma unroll
    for (int d = 0; d < 64; ++d) dst[base + (size_t)(w * 64 + d) * DD] = vbuf[d] * sc;
}

// ---------------------------------------------------------------------------
// Kernel 4: hmean[b][t][e] = sum_d ob[b][t][d] * alpha[b][d][e]
// Tile 128(t) x 64(e), KT=16, 8x4 acc. Same 1-barrier double-buffer pipeline;
// A transpose-staged (pad 132; staging write = 2-way bank alias = free).
// grid = (4 e-tiles, 8 t-tiles, B)
// ---------------------------------------------------------------------------
__global__ __launch_bounds__(256) void k_hmean(const float* __restrict__ ob,
                                               const float* __restrict__ alpha,
                                               float* __restrict__ hm) {
    __shared__ float As[2][16][132];  // [buf][k][t-local]
    __shared__ float Bs[2][16][64];   // [buf][k][e-local]
    const int tid = threadIdx.x;
    const int b = blockIdx.z;
    const int t0 = blockIdx.y * 128;
    const int e0 = blockIdx.x * 64;
    const float* pA = ob + (size_t)b * TT * DD;
    const float* pB = alpha + (size_t)b * DD * DD;
    const int mm = tid >> 2;          // 0..63
    const int kk4 = (tid & 3) * 4;    // 0..12
    const int bkr = tid >> 4;
    const int bec = (tid & 15) * 4;
    const int m0 = (tid >> 4) * 8;
    const int n0 = (tid & 15) * 4;
    float4 va0, va1, rb;
    float acc[8][4] = {};

    const int NT = DD / 16;  // 16 k-tiles
    va0 = *reinterpret_cast<const float4*>(&pA[(size_t)(t0 + mm) * DD + kk4]);
    va1 = *reinterpret_cast<const float4*>(&pA[(size_t)(t0 + 64 + mm) * DD + kk4]);
    rb  = *reinterpret_cast<const float4*>(&pB[(size_t)bkr * DD + e0 + bec]);
    {
        As[0][kk4 + 0][mm] = va0.x; As[0][kk4 + 1][mm] = va0.y;
        As[0][kk4 + 2][mm] = va0.z; As[0][kk4 + 3][mm] = va0.w;
        As[0][kk4 + 0][64 + mm] = va1.x; As[0][kk4 + 1][64 + mm] = va1.y;
        As[0][kk4 + 2][64 + mm] = va1.z; As[0][kk4 + 3][64 + mm] = va1.w;
        *reinterpret_cast<float4*>(&Bs[0][bkr][bec]) = rb;
    }

    for (int t = 0; t < NT; ++t) {
        if (t + 1 < NT) {
            const int k0 = (t + 1) * 16;
            va0 = *reinterpret_cast<const float4*>(&pA[(size_t)(t0 + mm) * DD + k0 + kk4]);
            va1 = *reinterpret_cast<const float4*>(&pA[(size_t)(t0 + 64 + mm) * DD + k0 + kk4]);
            rb  = *reinterpret_cast<const float4*>(&pB[(size_t)(k0 + bkr) * DD + e0 + bec]);
        }
        __syncthreads();
        const int cur = t & 1;
#pragma unroll
        for (int k = 0; k < 16; ++k) {
            const float4 a0 = *reinterpret_cast<const float4*>(&As[cur][k][m0]);
            const float4 a1 = *reinterpret_cast<const float4*>(&As[cur][k][m0 + 4]);
            const float4 b4 = *reinterpret_cast<const float4*>(&Bs[cur][k][n0]);
            const float av[8] = {a0.x, a0.y, a0.z, a0.w, a1.x, a1.y, a1.z, a1.w};
            const float bv[4] = {b4.x, b4.y, b4.z, b4.w};
#pragma unroll
            for (int i = 0; i < 8; ++i)
#pragma unroll
                for (int j = 0; j < 4; ++j) acc[i][j] += av[i] * bv[j];
        }
        if (t + 1 < NT) {
            const int nxt = (t + 1) & 1;
            As[nxt][kk4 + 0][mm] = va0.x; As[nxt][kk4 + 1][mm] = va0.y;
            As[nxt][kk4 + 2][mm] = va0.z; As[nxt][kk4 + 3][mm] = va0.w;
            As[nxt][kk4 + 0][64 + mm] = va1.x; As[nxt][kk4 + 1][64 + mm] = va1.y;
            As[nxt][kk4 + 2][64 + mm] = va1.z; As[nxt][kk4 + 3][64 + mm] = va1.w;
            *reinterpret_cast<float4*>(&Bs[nxt][bkr][bec]) = rb;
        }
    }
    float* out = hm + ((size_t)b * TT + t0 + m0) * DD + e0 + n0;
#pragma unroll
    for (int i = 0; i < 8; ++i) {
        const float4 v = {acc[i][0], acc[i][1], acc[i][2], acc[i][3]};
        *reinterpret_cast<float4*>(&out[(size_t)i * DD]) = v;
    }
}

// ---------------------------------------------------------------------------
// Kernel 5: persp[b][t][p] = num / (sqrt(sa)*sqrt(sh)).
// COALESCED lane layout: q = lane&7 (d-slice), r = lane>>3 (row in wave).
// Lane q owns the strided d-set {quad*32 + q*4 .. +3} (sums are order-
// independent) so each global b128 load is 8 lanes x 16B = 128B contiguous
// per row-group -> zero overfetch (fixes the 4x FETCH_SIZE of R1 layout).
// w2 = W^2 in natural order in LDS; per-(p,quad) b128 read spans all 32
// banks across q and broadcasts across r -> conflict-free, no padding.
// Reduce across q = lane bits 0..2 -> shfl_xor 1,2,4.
// grid = BB*TT/32 blocks of 256.
// ---------------------------------------------------------------------------
__global__ __launch_bounds__(256) void k_persp(const float* __restrict__ inp_a,
                                               const float* __restrict__ hmean,
                                               const float* __restrict__ W,
                                               float* __restrict__ out) {
    __shared__ float w2L[PP * DD];  // 20 KB, natural order
    for (int i = threadIdx.x; i < PP * DD; i += 256) {
        const float w = W[i];
        w2L[i] = w * w;
    }
    __syncthreads();
    const int wave = threadIdx.x >> 6;
    const int lane = threadIdx.x & 63;
    const int q = lane & 7;   // d-slice
    const int r = lane >> 3;  // row within wave
    const size_t row = (size_t)blockIdx.x * 32 + wave * 8 + r;
    const float* pa = inp_a + row * DD + q * 4;
    const float* ph = hmean + row * DD + q * 4;

    float acc[PP][3] = {};
#pragma unroll
    for (int quad = 0; quad < 8; ++quad) {
        const float4 a4 = *reinterpret_cast<const float4*>(pa + quad * 32);
        const float4 h4 = *reinterpret_cast<const float4*>(ph + quad * 32);
        const float ah[4] = {a4.x * h4.x, a4.y * h4.y, a4.z * h4.z, a4.w * h4.w};
        const float aa[4] = {a4.x * a4.x, a4.y * a4.y, a4.z * a4.z, a4.w * a4.w};
        const float hh[4] = {h4.x * h4.x, h4.y * h4.y, h4.z * h4.z, h4.w * h4.w};
#pragma unroll
        for (int p = 0; p < PP; ++p) {
            const float4 w4 =
                *reinterpret_cast<const float4*>(&w2L[p * DD + quad * 32 + q * 4]);
            const float wv[4] = {w4.x, w4.y, w4.z, w4.w};
#pragma unroll
            for (int j = 0; j < 4; ++j) {
                acc[p][0] += ah[j] * wv[j];
                acc[p][1] += aa[j] * wv[j];
                acc[p][2] += hh[j] * wv[j];
            }
        }
    }
    // reduce the 8 q-slices (lane bits 0..2)
#pragma unroll
    for (int p = 0; p < PP; ++p)
#pragma unroll
        for (int s = 0; s < 3; ++s) {
            float v = acc[p][s];
            v += __shfl_xor(v, 1);
            v += __shfl_xor(v, 2);
            v += __shfl_xor(v, 4);
            acc[p][s] = v;
        }
    if (q == 0) {
        float res[PP];
#pragma unroll
        for (int p = 0; p < PP; ++p) {
            const float sa = sqrtf(fmaxf(acc[p][1], EPS));
            const float sh = sqrtf(fmaxf(acc[p][2], EPS));
            res[p] = acc[p][0] / (sa * sh);
        }
        float* o1 = out + row * PP;
        float* o2 = o1 + (size_t)BB * TT * PP;
#pragma unroll
        for (int k = 0; k < 5; ++k) {
            const float4 v = reinterpret_cast<const float4*>(res)[k];
            reinterpret_cast<float4*>(o1)[k] = v;
            reinterpret_cast<float4*>(o2)[k] = v;
        }
    }
}

// ---------------------------------------------------------------------------
extern "C" void kernel_launch(void* const* d_in, const int* in_sizes, int n_in,
                              void* d_out, int out_size, void* d_ws, size_t ws_size,
                              hipStream_t stream) {
    const float* inp_a = (const float*)d_in[0];
    const float* inp_b = (const float*)d_in[1];
    const float* W = (const float*)d_in[2];
    float* out = (float*)d_out;

    float* oa = (float*)d_ws;                        // 8.39M floats
    float* ob = oa + (size_t)BB * TT * DD;           // 8.39M floats
    float* apart = ob + (size_t)BB * TT * DD;        // 2 x 2.10M floats
    float* apart1 = apart + (size_t)BB * DD * DD;
    float* alpha = apart;                            // final alpha overwrites half 0
    float* hmean = oa;                               // reuse: oa dead after k_alpha

    k_rownorm<<<BB * TT / 4, 256, 0, stream>>>(inp_a, oa);
    k_rownorm<<<BB * TT / 4, 256, 0, stream>>>(inp_b, ob);
    k_alpha<<<dim3(8, 2, BB), 256, 0, stream>>>(oa, ob, apart);
    k_alphanorm<<<dim3(4, BB), 256, 0, stream>>>(apart, apart1, alpha);
    k_hmean<<<dim3(4, 8, BB), 256, 0, stream>>>(ob, alpha, hmean);
    k_persp<<<BB * TT / 32, 256, 0, stream>>>(inp_a, hmean, W, out);
}

// Round 5
// 203.196 us; speedup vs baseline: 1.8446x; 1.3416x over previous
//
#include <hip/hip_runtime.h>
#include <math.h>

#define BB 32
#define TT 1024
#define DD 256
#define PP 20
constexpr float EPS = 1e-12f;

typedef __attribute__((ext_vector_type(8))) short bf16x8;
typedef __attribute__((ext_vector_type(4))) float f32x4;

// round-to-nearest-even fp32 -> bf16
static __device__ __forceinline__ unsigned short f2bf(float f) {
    union { float f; unsigned int u; } c; c.f = f;
    const unsigned int u = c.u;
    return (unsigned short)((u + 0x7FFFu + ((u >> 16) & 1u)) >> 16);
}

// ---------------------------------------------------------------------------
// k_prep: per batch slab of 64 t-rows: row l2-norm, cvt bf16, and
//   outT[b][d][t]  <- normalized, TRANSPOSED (K-minor for MFMA A/B)
//   outN[b][t][d]  <- RAW bf16 natural (for k_hmean's A; norm cancels in persp)
// LDS transpose tile [256 d][64 t + pad2]. grid = (TT/64, BB).
// ---------------------------------------------------------------------------
__global__ __launch_bounds__(256) void k_prep(const float* __restrict__ in,
                                              unsigned short* __restrict__ outT,
                                              unsigned short* __restrict__ outN) {
    __shared__ unsigned short Tls[DD][66];
    const int b = blockIdx.y;
    const int t0 = blockIdx.x * 64;
    const int wave = threadIdx.x >> 6;
    const int lane = threadIdx.x & 63;
    const float* src = in + (size_t)b * TT * DD;
    for (int pass = 0; pass < 16; ++pass) {
        const int tl = pass * 4 + wave;  // 0..63
        const int t = t0 + tl;
        const float4 v =
            *reinterpret_cast<const float4*>(&src[(size_t)t * DD + lane * 4]);
        float ss = v.x * v.x + v.y * v.y + v.z * v.z + v.w * v.w;
#pragma unroll
        for (int off = 32; off; off >>= 1) ss += __shfl_xor(ss, off);
        const float sc = 1.0f / sqrtf(fmaxf(ss, EPS));
        Tls[lane * 4 + 0][tl] = f2bf(v.x * sc);
        Tls[lane * 4 + 1][tl] = f2bf(v.y * sc);
        Tls[lane * 4 + 2][tl] = f2bf(v.z * sc);
        Tls[lane * 4 + 3][tl] = f2bf(v.w * sc);
        if (outN) {
            ushort4 r;
            r.x = f2bf(v.x); r.y = f2bf(v.y); r.z = f2bf(v.z); r.w = f2bf(v.w);
            *reinterpret_cast<ushort4*>(&outN[((size_t)b * TT + t) * DD + lane * 4]) = r;
        }
    }
    __syncthreads();
    // coalesced transposed write: thread d owns row d, 64 t = 8 x uint4
    const int d = threadIdx.x;
    unsigned short* dst = outT + ((size_t)b * DD + d) * TT + t0;
#pragma unroll
    for (int k = 0; k < 8; ++k) {
        unsigned short tmp[8];
#pragma unroll
        for (int j = 0; j < 8; ++j) tmp[j] = Tls[d][k * 8 + j];
        *reinterpret_cast<uint4*>(&dst[k * 8]) = *reinterpret_cast<const uint4*>(tmp);
    }
}

// ---------------------------------------------------------------------------
// k_gemm<M,N,K>: C[b][m][n] = sum_k A[b][m][k] * B[b][n][k]   (bf16 in, f32 out)
// 64x64 tile, 4 waves (2x2), wave-tile 32x32 = 2x2 MFMA frags, K-step 32.
// LDS rows padded to 40 ushorts (80B): frag b128 reads land 2-way (free).
// R3-style 1-barrier reg-prefetch double buffer.
// grid = ((M/64)*(N/64), BB)
// ---------------------------------------------------------------------------
template <int M, int N, int K>
__global__ __launch_bounds__(256) void k_gemm(const unsigned short* __restrict__ A,
                                              const unsigned short* __restrict__ B,
                                              float* __restrict__ C) {
    __shared__ unsigned short As[2][64][40];
    __shared__ unsigned short Bs[2][64][40];
    const int tid = threadIdx.x;
    const int b = blockIdx.y;
    constexpr int NTILES = N / 64;
    const int m0 = (blockIdx.x / NTILES) * 64;
    const int n0 = (blockIdx.x % NTILES) * 64;
    const unsigned short* pA = A + (size_t)b * M * K + (size_t)m0 * K;
    const unsigned short* pB = B + (size_t)b * N * K + (size_t)n0 * K;
    const int srow = tid >> 2;          // staging row 0..63
    const int skoff = (tid & 3) * 8;    // staging k-offset (bf16 units)
    const int wave = tid >> 6;
    const int lane = tid & 63;
    const int wm = (wave >> 1) * 32;
    const int wn = (wave & 1) * 32;
    const int fr = lane & 15;           // fragment row/col
    const int fc = lane >> 4;           // k-chunk 0..3 (8 bf16 each)
    f32x4 acc[2][2] = {};
    uint4 ra, rb;

    ra = *reinterpret_cast<const uint4*>(&pA[(size_t)srow * K + skoff]);
    rb = *reinterpret_cast<const uint4*>(&pB[(size_t)srow * K + skoff]);
    *reinterpret_cast<uint4*>(&As[0][srow][skoff]) = ra;
    *reinterpret_cast<uint4*>(&Bs[0][srow][skoff]) = rb;

    constexpr int NT = K / 32;
    for (int t = 0; t < NT; ++t) {
        if (t + 1 < NT) {
            const int k0 = (t + 1) * 32;
            ra = *reinterpret_cast<const uint4*>(&pA[(size_t)srow * K + k0 + skoff]);
            rb = *reinterpret_cast<const uint4*>(&pB[(size_t)srow * K + k0 + skoff]);
        }
        __syncthreads();
        const int cur = t & 1;
        bf16x8 af[2], bfr[2];
#pragma unroll
        for (int i = 0; i < 2; ++i) {
            af[i]  = *reinterpret_cast<const bf16x8*>(&As[cur][wm + i * 16 + fr][fc * 8]);
            bfr[i] = *reinterpret_cast<const bf16x8*>(&Bs[cur][wn + i * 16 + fr][fc * 8]);
        }
#pragma unroll
        for (int i = 0; i < 2; ++i)
#pragma unroll
            for (int j = 0; j < 2; ++j)
                acc[i][j] = __builtin_amdgcn_mfma_f32_16x16x32_bf16(af[i], bfr[j],
                                                                    acc[i][j], 0, 0, 0);
        if (t + 1 < NT) {
            const int nxt = (t + 1) & 1;
            *reinterpret_cast<uint4*>(&As[nxt][srow][skoff]) = ra;
            *reinterpret_cast<uint4*>(&Bs[nxt][srow][skoff]) = rb;
        }
    }
    // C/D layout (m89-verified): col = lane&15, row = (lane>>4)*4 + reg
    float* pC = C + (size_t)b * M * N;
#pragma unroll
    for (int i = 0; i < 2; ++i)
#pragma unroll
        for (int j = 0; j < 2; ++j) {
            const int rbase = m0 + wm + i * 16 + fc * 4;
            const int col = n0 + wn + j * 16 + fr;
#pragma unroll
            for (int r = 0; r < 4; ++r)
                pC[(size_t)(rbase + r) * N + col] = acc[i][j][r];
        }
}

// ---------------------------------------------------------------------------
// k_alphanorm2: alphaT rows (fixed (b,e), all d = contiguous) -> l2 norm ->
// bf16. One wave per row, 4 rows/block. grid = BB*DD/4.
// ---------------------------------------------------------------------------
__global__ __launch_bounds__(256) void k_alphanorm2(const float* __restrict__ src,
                                                    unsigned short* __restrict__ dst) {
    const int wave = threadIdx.x >> 6;
    const int lane = threadIdx.x & 63;
    const size_t row = (size_t)blockIdx.x * 4 + wave;
    const float4 v = reinterpret_cast<const float4*>(src + row * DD)[lane];
    float s = v.x * v.x + v.y * v.y + v.z * v.z + v.w * v.w;
#pragma unroll
    for (int off = 32; off; off >>= 1) s += __shfl_xor(s, off);
    const float sc = 1.0f / sqrtf(fmaxf(s, EPS));
    ushort4 r;
    r.x = f2bf(v.x * sc); r.y = f2bf(v.y * sc);
    r.z = f2bf(v.z * sc); r.w = f2bf(v.w * sc);
    reinterpret_cast<ushort4*>(dst + row * DD)[lane] = r;
}

// ---------------------------------------------------------------------------
// k_persp: unchanged from R3 (verified: coalesced layout, zero overfetch).
// ---------------------------------------------------------------------------
__global__ __launch_bounds__(256) void k_persp(const float* __restrict__ inp_a,
                                               const float* __restrict__ hmean,
                                               const float* __restrict__ W,
                                               float* __restrict__ out) {
    __shared__ float w2L[PP * DD];
    for (int i = threadIdx.x; i < PP * DD; i += 256) {
        const float w = W[i];
        w2L[i] = w * w;
    }
    __syncthreads();
    const int wave = threadIdx.x >> 6;
    const int lane = threadIdx.x & 63;
    const int q = lane & 7;
    const int r = lane >> 3;
    const size_t row = (size_t)blockIdx.x * 32 + wave * 8 + r;
    const float* pa = inp_a + row * DD + q * 4;
    const float* ph = hmean + row * DD + q * 4;

    float acc[PP][3] = {};
#pragma unroll
    for (int quad = 0; quad < 8; ++quad) {
        const float4 a4 = *reinterpret_cast<const float4*>(pa + quad * 32);
        const float4 h4 = *reinterpret_cast<const float4*>(ph + quad * 32);
        const float ah[4] = {a4.x * h4.x, a4.y * h4.y, a4.z * h4.z, a4.w * h4.w};
        const float aa[4] = {a4.x * a4.x, a4.y * a4.y, a4.z * a4.z, a4.w * a4.w};
        const float hh[4] = {h4.x * h4.x, h4.y * h4.y, h4.z * h4.z, h4.w * h4.w};
#pragma unroll
        for (int p = 0; p < PP; ++p) {
            const float4 w4 =
                *reinterpret_cast<const float4*>(&w2L[p * DD + quad * 32 + q * 4]);
            const float wv[4] = {w4.x, w4.y, w4.z, w4.w};
#pragma unroll
            for (int j = 0; j < 4; ++j) {
                acc[p][0] += ah[j] * wv[j];
                acc[p][1] += aa[j] * wv[j];
                acc[p][2] += hh[j] * wv[j];
            }
        }
    }
#pragma unroll
    for (int p = 0; p < PP; ++p)
#pragma unroll
        for (int s = 0; s < 3; ++s) {
            float v = acc[p][s];
            v += __shfl_xor(v, 1);
            v += __shfl_xor(v, 2);
            v += __shfl_xor(v, 4);
            acc[p][s] = v;
        }
    if (q == 0) {
        float res[PP];
#pragma unroll
        for (int p = 0; p < PP; ++p) {
            const float sa = sqrtf(fmaxf(acc[p][1], EPS));
            const float sh = sqrtf(fmaxf(acc[p][2], EPS));
            res[p] = acc[p][0] / (sa * sh);
        }
        float* o1 = out + row * PP;
        float* o2 = o1 + (size_t)BB * TT * PP;
#pragma unroll
        for (int k = 0; k < 5; ++k) {
            const float4 v = reinterpret_cast<const float4*>(res)[k];
            reinterpret_cast<float4*>(o1)[k] = v;
            reinterpret_cast<float4*>(o2)[k] = v;
        }
    }
}

// ---------------------------------------------------------------------------
extern "C" void kernel_launch(void* const* d_in, const int* in_sizes, int n_in,
                              void* d_out, int out_size, void* d_ws, size_t ws_size,
                              hipStream_t stream) {
    const float* inp_a = (const float*)d_in[0];
    const float* inp_b = (const float*)d_in[1];
    const float* W = (const float*)d_in[2];
    float* out = (float*)d_out;

    // workspace (63 MB): [oaT|obT bf16: 33.6MB, later reused as hmean f32]
    //                    [bnat bf16 16.8MB][alphaT f32 8.4MB][alphaTb bf16 4.2MB]
    unsigned short* oaT = (unsigned short*)d_ws;                 // [b][e][t]
    unsigned short* obT = oaT + (size_t)BB * DD * TT;            // [b][d][t]
    float* hmean = (float*)d_ws;                                 // [b][t][e] (reuse)
    unsigned short* bnat = obT + (size_t)BB * DD * TT;           // [b][t][d] raw
    float* alphaT = (float*)(bnat + (size_t)BB * TT * DD);       // [b][e][d]
    unsigned short* alphaTb = (unsigned short*)(alphaT + (size_t)BB * DD * DD);

    k_prep<<<dim3(TT / 64, BB), 256, 0, stream>>>(inp_a, oaT, nullptr);
    k_prep<<<dim3(TT / 64, BB), 256, 0, stream>>>(inp_b, obT, bnat);
    // alphaT[e][d] = sum_t oaT[e][t] * obT[d][t]
    k_gemm<DD, DD, TT><<<dim3(16, BB), 256, 0, stream>>>(oaT, obT, alphaT);
    k_alphanorm2<<<BB * DD / 4, 256, 0, stream>>>(alphaT, alphaTb);
    // hmean[t][e] = sum_d bnat[t][d] * alphaTb[e][d]  (row scale cancels in persp)
    k_gemm<TT, DD, DD><<<dim3(64, BB), 256, 0, stream>>>(bnat, alphaTb, hmean);
    k_persp<<<BB * TT / 32, 256, 0, stream>>>(inp_a, hmean, W, out);
}

// Round 6
// 184.029 us; speedup vs baseline: 2.0367x; 1.1042x over previous
//
#include <hip/hip_runtime.h>
#include <math.h>

#define BB 32
#define TT 1024
#define DD 256
#define PP 20
constexpr float EPS = 1e-12f;

typedef __attribute__((ext_vector_type(8))) short bf16x8;
typedef __attribute__((ext_vector_type(4))) float f32x4;

// round-to-nearest-even fp32 -> bf16
static __device__ __forceinline__ unsigned short f2bf(float f) {
    union { float f; unsigned int u; } c; c.f = f;
    const unsigned int u = c.u;
    return (unsigned short)((u + 0x7FFFu + ((u >> 16) & 1u)) >> 16);
}

// ---------------------------------------------------------------------------
// k_prep: per batch slab of 64 t-rows: row l2-norm, cvt bf16, and
//   outT[b][d][t]  <- normalized, TRANSPOSED (K-minor for MFMA A/B)
//   outN[b][t][d]  <- RAW bf16 natural (for k_hmean's A; norm cancels in persp)
// ---------------------------------------------------------------------------
__global__ __launch_bounds__(256) void k_prep(const float* __restrict__ in,
                                              unsigned short* __restrict__ outT,
                                              unsigned short* __restrict__ outN) {
    __shared__ unsigned short Tls[DD][66];
    const int b = blockIdx.y;
    const int t0 = blockIdx.x * 64;
    const int wave = threadIdx.x >> 6;
    const int lane = threadIdx.x & 63;
    const float* src = in + (size_t)b * TT * DD;
    for (int pass = 0; pass < 16; ++pass) {
        const int tl = pass * 4 + wave;  // 0..63
        const int t = t0 + tl;
        const float4 v =
            *reinterpret_cast<const float4*>(&src[(size_t)t * DD + lane * 4]);
        float ss = v.x * v.x + v.y * v.y + v.z * v.z + v.w * v.w;
#pragma unroll
        for (int off = 32; off; off >>= 1) ss += __shfl_xor(ss, off);
        const float sc = 1.0f / sqrtf(fmaxf(ss, EPS));
        Tls[lane * 4 + 0][tl] = f2bf(v.x * sc);
        Tls[lane * 4 + 1][tl] = f2bf(v.y * sc);
        Tls[lane * 4 + 2][tl] = f2bf(v.z * sc);
        Tls[lane * 4 + 3][tl] = f2bf(v.w * sc);
        if (outN) {
            ushort4 r;
            r.x = f2bf(v.x); r.y = f2bf(v.y); r.z = f2bf(v.z); r.w = f2bf(v.w);
            *reinterpret_cast<ushort4*>(&outN[((size_t)b * TT + t) * DD + lane * 4]) = r;
        }
    }
    __syncthreads();
    const int d = threadIdx.x;
    unsigned short* dst = outT + ((size_t)b * DD + d) * TT + t0;
#pragma unroll
    for (int k = 0; k < 8; ++k) {
        unsigned short tmp[8];
#pragma unroll
        for (int j = 0; j < 8; ++j) tmp[j] = Tls[d][k * 8 + j];
        *reinterpret_cast<uint4*>(&dst[k * 8]) = *reinterpret_cast<const uint4*>(tmp);
    }
}

// ---------------------------------------------------------------------------
// k_gemm<M,N,K,KS>: C[z][b][m][n] = sum_{k in slice z} A[b][m][k]*B[b][n][k]
// bf16 in, f32 out. 64x64 tile, 4 waves (2x2), 2x2 16x16x32 frags/wave.
// 1-barrier reg-prefetch double buffer. grid = ((M/64)*(N/64), BB, KS).
// ---------------------------------------------------------------------------
template <int M, int N, int K, int KS>
__global__ __launch_bounds__(256) void k_gemm(const unsigned short* __restrict__ A,
                                              const unsigned short* __restrict__ B,
                                              float* __restrict__ C) {
    __shared__ unsigned short As[2][64][40];
    __shared__ unsigned short Bs[2][64][40];
    const int tid = threadIdx.x;
    const int b = blockIdx.y;
    constexpr int NTILES = N / 64;
    constexpr int KSL = K / KS;
    const int m0 = (blockIdx.x / NTILES) * 64;
    const int n0 = (blockIdx.x % NTILES) * 64;
    const int kbeg = blockIdx.z * KSL;
    const unsigned short* pA = A + (size_t)b * M * K + (size_t)m0 * K + kbeg;
    const unsigned short* pB = B + (size_t)b * N * K + (size_t)n0 * K + kbeg;
    const int srow = tid >> 2;
    const int skoff = (tid & 3) * 8;
    const int wave = tid >> 6;
    const int lane = tid & 63;
    const int wm = (wave >> 1) * 32;
    const int wn = (wave & 1) * 32;
    const int fr = lane & 15;
    const int fc = lane >> 4;
    f32x4 acc[2][2] = {};
    uint4 ra, rb;

    ra = *reinterpret_cast<const uint4*>(&pA[(size_t)srow * K + skoff]);
    rb = *reinterpret_cast<const uint4*>(&pB[(size_t)srow * K + skoff]);
    *reinterpret_cast<uint4*>(&As[0][srow][skoff]) = ra;
    *reinterpret_cast<uint4*>(&Bs[0][srow][skoff]) = rb;

    constexpr int NT = KSL / 32;
    for (int t = 0; t < NT; ++t) {
        if (t + 1 < NT) {
            const int k0 = (t + 1) * 32;
            ra = *reinterpret_cast<const uint4*>(&pA[(size_t)srow * K + k0 + skoff]);
            rb = *reinterpret_cast<const uint4*>(&pB[(size_t)srow * K + k0 + skoff]);
        }
        __syncthreads();
        const int cur = t & 1;
        bf16x8 af[2], bfr[2];
#pragma unroll
        for (int i = 0; i < 2; ++i) {
            af[i]  = *reinterpret_cast<const bf16x8*>(&As[cur][wm + i * 16 + fr][fc * 8]);
            bfr[i] = *reinterpret_cast<const bf16x8*>(&Bs[cur][wn + i * 16 + fr][fc * 8]);
        }
#pragma unroll
        for (int i = 0; i < 2; ++i)
#pragma unroll
            for (int j = 0; j < 2; ++j)
                acc[i][j] = __builtin_amdgcn_mfma_f32_16x16x32_bf16(af[i], bfr[j],
                                                                    acc[i][j], 0, 0, 0);
        if (t + 1 < NT) {
            const int nxt = (t + 1) & 1;
            *reinterpret_cast<uint4*>(&As[nxt][srow][skoff]) = ra;
            *reinterpret_cast<uint4*>(&Bs[nxt][srow][skoff]) = rb;
        }
    }
    float* pC = C + (size_t)blockIdx.z * BB * M * N + (size_t)b * M * N;
#pragma unroll
    for (int i = 0; i < 2; ++i)
#pragma unroll
        for (int j = 0; j < 2; ++j) {
            const int rbase = m0 + wm + i * 16 + fc * 4;
            const int col = n0 + wn + j * 16 + fr;
#pragma unroll
            for (int r = 0; r < 4; ++r)
                pC[(size_t)(rbase + r) * N + col] = acc[i][j][r];
        }
}

// ---------------------------------------------------------------------------
// k_alphanorm2: row = (b,e), 256 contiguous d. Sums optional second split-K
// partial, l2-normalizes, writes bf16. One wave/row, 4 rows/block.
// ---------------------------------------------------------------------------
__global__ __launch_bounds__(256) void k_alphanorm2(const float* __restrict__ p0,
                                                    const float* __restrict__ p1,
                                                    unsigned short* __restrict__ dst) {
    const int wave = threadIdx.x >> 6;
    const int lane = threadIdx.x & 63;
    const size_t row = (size_t)blockIdx.x * 4 + wave;
    float4 v = reinterpret_cast<const float4*>(p0 + row * DD)[lane];
    if (p1) {
        const float4 w = reinterpret_cast<const float4*>(p1 + row * DD)[lane];
        v.x += w.x; v.y += w.y; v.z += w.z; v.w += w.w;
    }
    float s = v.x * v.x + v.y * v.y + v.z * v.z + v.w * v.w;
#pragma unroll
    for (int off = 32; off; off >>= 1) s += __shfl_xor(s, off);
    const float sc = 1.0f / sqrtf(fmaxf(s, EPS));
    ushort4 r;
    r.x = f2bf(v.x * sc); r.y = f2bf(v.y * sc);
    r.z = f2bf(v.z * sc); r.w = f2bf(v.w * sc);
    reinterpret_cast<ushort4*>(dst + row * DD)[lane] = r;
}

// ---------------------------------------------------------------------------
// k_persp2: persp via MFMA. num|sa|sh = (ah|aa|hh)·W2^T, K=256, N=32 (20 used).
// A-fragments computed IN REGISTERS from fp32 a,h (lane (fr,fc) loads exactly
// its fragment rows' k-chunk) — no LDS for A, no shfl anywhere.
// B = w2 pre-packed per-lane fragments in LDS (16 KB, linear, conflict-free).
// C layout: row = fc*4+r, col(p) = j*16+fr -> num/sa/sh of one (row,p) are in
// the SAME lane & reg -> ratio is lane-local. Block = 4 waves x 16 rows.
// grid = BB*TT/64.
// ---------------------------------------------------------------------------
__global__ __launch_bounds__(256) void k_persp2(const float* __restrict__ inp_a,
                                                const float* __restrict__ hmean,
                                                const float* __restrict__ W,
                                                float* __restrict__ out) {
    __shared__ uint4 Bpk[8 * 2 * 64];  // [kstep][j][lane], 16 KB
    const int tid = threadIdx.x;
#pragma unroll
    for (int i = 0; i < 4; ++i) {
        const int ne = tid + i * 256;
        const int kstep = ne >> 7;
        const int j = (ne >> 6) & 1;
        const int ln = ne & 63;
        const int p = j * 16 + (ln & 15);
        const int k0 = kstep * 32 + (ln >> 4) * 8;
        unsigned short w8[8];
        if (p < PP) {
#pragma unroll
            for (int e = 0; e < 8; ++e) {
                const float w = W[p * DD + k0 + e];
                w8[e] = f2bf(w * w);
            }
        } else {
#pragma unroll
            for (int e = 0; e < 8; ++e) w8[e] = 0;
        }
        Bpk[ne] = *reinterpret_cast<const uint4*>(w8);
    }
    __syncthreads();

    const int wave = tid >> 6;
    const int lane = tid & 63;
    const int fr = lane & 15;
    const int fc = lane >> 4;
    const size_t row = (size_t)blockIdx.x * 64 + wave * 16 + fr;
    const float* pa = inp_a + row * DD + fc * 8;
    const float* ph = hmean + row * DD + fc * 8;
    const bf16x8* bp = reinterpret_cast<const bf16x8*>(Bpk);

    f32x4 acc[3][2] = {};
    float4 a0 = *reinterpret_cast<const float4*>(pa);
    float4 a1 = *reinterpret_cast<const float4*>(pa + 4);
    float4 h0 = *reinterpret_cast<const float4*>(ph);
    float4 h1 = *reinterpret_cast<const float4*>(ph + 4);

    for (int t = 0; t < 8; ++t) {
        float4 na0, na1, nh0, nh1;
        if (t < 7) {
            na0 = *reinterpret_cast<const float4*>(pa + (t + 1) * 32);
            na1 = *reinterpret_cast<const float4*>(pa + (t + 1) * 32 + 4);
            nh0 = *reinterpret_cast<const float4*>(ph + (t + 1) * 32);
            nh1 = *reinterpret_cast<const float4*>(ph + (t + 1) * 32 + 4);
        }
        const float av[8] = {a0.x, a0.y, a0.z, a0.w, a1.x, a1.y, a1.z, a1.w};
        const float hv[8] = {h0.x, h0.y, h0.z, h0.w, h1.x, h1.y, h1.z, h1.w};
        unsigned short ah[8], aa[8], hh[8];
#pragma unroll
        for (int e = 0; e < 8; ++e) {
            ah[e] = f2bf(av[e] * hv[e]);
            aa[e] = f2bf(av[e] * av[e]);
            hh[e] = f2bf(hv[e] * hv[e]);
        }
        const bf16x8 pf0 = *reinterpret_cast<const bf16x8*>(ah);
        const bf16x8 pf1 = *reinterpret_cast<const bf16x8*>(aa);
        const bf16x8 pf2 = *reinterpret_cast<const bf16x8*>(hh);
        const bf16x8 bf0 = bp[(t * 2 + 0) * 64 + lane];
        const bf16x8 bf1 = bp[(t * 2 + 1) * 64 + lane];
        acc[0][0] = __builtin_amdgcn_mfma_f32_16x16x32_bf16(pf0, bf0, acc[0][0], 0, 0, 0);
        acc[0][1] = __builtin_amdgcn_mfma_f32_16x16x32_bf16(pf0, bf1, acc[0][1], 0, 0, 0);
        acc[1][0] = __builtin_amdgcn_mfma_f32_16x16x32_bf16(pf1, bf0, acc[1][0], 0, 0, 0);
        acc[1][1] = __builtin_amdgcn_mfma_f32_16x16x32_bf16(pf1, bf1, acc[1][1], 0, 0, 0);
        acc[2][0] = __builtin_amdgcn_mfma_f32_16x16x32_bf16(pf2, bf0, acc[2][0], 0, 0, 0);
        acc[2][1] = __builtin_amdgcn_mfma_f32_16x16x32_bf16(pf2, bf1, acc[2][1], 0, 0, 0);
        a0 = na0; a1 = na1; h0 = nh0; h1 = nh1;
    }

    const size_t rowbase = (size_t)blockIdx.x * 64 + wave * 16 + fc * 4;
#pragma unroll
    for (int j = 0; j < 2; ++j) {
        const int p = j * 16 + fr;
        if (p < PP) {
#pragma unroll
            for (int r = 0; r < 4; ++r) {
                const float num = acc[0][j][r];
                const float sa = sqrtf(fmaxf(acc[1][j][r], EPS));
                const float sh = sqrtf(fmaxf(acc[2][j][r], EPS));
                const float v = num / (sa * sh);
                const size_t o = (rowbase + r) * PP + p;
                out[o] = v;
                out[(size_t)BB * TT * PP + o] = v;
            }
        }
    }
}

// ---------------------------------------------------------------------------
extern "C" void kernel_launch(void* const* d_in, const int* in_sizes, int n_in,
                              void* d_out, int out_size, void* d_ws, size_t ws_size,
                              hipStream_t stream) {
    const float* inp_a = (const float*)d_in[0];
    const float* inp_b = (const float*)d_in[1];
    const float* W = (const float*)d_in[2];
    float* out = (float*)d_out;

    const size_t NTD = (size_t)BB * TT * DD;   // 8.39M
    const size_t NDD = (size_t)BB * DD * DD;   // 2.10M
    unsigned short* oaT = (unsigned short*)d_ws;          // [b][e][t] bf16
    unsigned short* obT = oaT + NTD;                      // [b][d][t] bf16
    float* hmean = (float*)d_ws;                          // [b][t][e] f32 (reuse)
    unsigned short* bnat = obT + NTD;                     // [b][t][d] bf16 raw
    float* aP0 = (float*)(bnat + NTD);                    // alphaT partial 0
    // split-K=2 needs 71,303,168 B of ws; fall back to single-K otherwise
    const bool SPLIT = ws_size >= (size_t)(NTD * 2 * 3 + NDD * 4 * 2 + NDD * 2);
    float* aP1 = SPLIT ? aP0 + NDD : nullptr;
    unsigned short* aTb = (unsigned short*)(aP0 + (SPLIT ? 2 * NDD : NDD));

    k_prep<<<dim3(TT / 64, BB), 256, 0, stream>>>(inp_a, oaT, nullptr);
    k_prep<<<dim3(TT / 64, BB), 256, 0, stream>>>(inp_b, obT, bnat);
    // alphaT[e][d] = sum_t oaT[e][t] * obT[d][t]
    if (SPLIT)
        k_gemm<DD, DD, TT, 2><<<dim3(16, BB, 2), 256, 0, stream>>>(oaT, obT, aP0);
    else
        k_gemm<DD, DD, TT, 1><<<dim3(16, BB, 1), 256, 0, stream>>>(oaT, obT, aP0);
    k_alphanorm2<<<BB * DD / 4, 256, 0, stream>>>(aP0, aP1, aTb);
    // hmean[t][e] = sum_d bnat[t][d] * aTb[e][d]  (row scale cancels in persp)
    k_gemm<TT, DD, DD, 1><<<dim3(64, BB, 1), 256, 0, stream>>>(bnat, aTb, hmean);
    k_persp2<<<BB * TT / 64, 256, 0, stream>>>(inp_a, hmean, W, out);
}